// Round 5
// baseline (556.414 us; speedup 1.0000x reference)
//
#include <hip/hip_runtime.h>
#include <stdint.h>

typedef __bf16 bf16x8 __attribute__((ext_vector_type(8)));
typedef float  f32x4  __attribute__((ext_vector_type(4)));

#define DEV __device__ __forceinline__

constexpr int Bc = 4, S = 2048, D = 1024, Hh = 16, DH = 64;
constexpr int Kdim = 1024;   // inner K of both GEMMs

DEV unsigned short f2bf(float f) {
    uint32_t u = __builtin_bit_cast(uint32_t, f);
    u += 0x7fff + ((u >> 16) & 1);   // RNE
    return (unsigned short)(u >> 16);
}
DEV bf16x8 ld8(const unsigned short* p) {
    uint4 u = *(const uint4*)p;
    return __builtin_bit_cast(bf16x8, u);
}
DEV uint4 pack8(float4 a, float4 b) {
    union { uint4 u; unsigned short s[8]; } r;
    r.s[0] = f2bf(a.x); r.s[1] = f2bf(a.y); r.s[2] = f2bf(a.z); r.s[3] = f2bf(a.w);
    r.s[4] = f2bf(b.x); r.s[5] = f2bf(b.y); r.s[6] = f2bf(b.z); r.s[7] = f2bf(b.w);
    return r.u;
}

// ---------- weight transpose + cvt (f32 [rows][cols] -> bf16 [cols][rows]) ------
__global__ __launch_bounds__(256) void transpose_cvt(const float* __restrict__ in,
                                                     unsigned short* __restrict__ out,
                                                     int rows, int cols) {
    __shared__ float t[32][33];
    int tx = threadIdx.x & 31, ty = threadIdx.x >> 5;  // 32 x 8
    int c = blockIdx.x * 32 + tx;
    int rbase = blockIdx.y * 32;
    for (int rr = 0; rr < 32; rr += 8)
        t[ty + rr][tx] = in[(size_t)(rbase + ty + rr) * cols + c];
    __syncthreads();
    int orbase = blockIdx.x * 32;
    for (int rr = 0; rr < 32; rr += 8)
        out[(size_t)(orbase + ty + rr) * rows + rbase + tx] = f2bf(t[tx][ty + rr]);
}

// ---------- GEMM: C[M,N] = A_f32[M,K] * Bt_bf16[N,K]^T + bias_f32 ---------------
// mode 0: scatter bf16 into q/k [B,H,S,DH] and V TRANSPOSED [B,H,DH,S]
// mode 1: write f32 outf [M,N]
__global__ __launch_bounds__(256) void gemm_bt(const float* __restrict__ A,
                                               const unsigned short* __restrict__ Bt,
                                               const float* __restrict__ bias,
                                               int mode,
                                               unsigned short* __restrict__ qo,
                                               unsigned short* __restrict__ ko,
                                               unsigned short* __restrict__ vo,
                                               float* __restrict__ outf) {
    __shared__ __align__(16) unsigned short As[128 * 32];
    __shared__ __align__(16) unsigned short Bs[128 * 32];
    const int tid = threadIdx.x;
    const int wave = tid >> 6, lane = tid & 63, g = lane >> 4, ln = lane & 15;
    const int wm = wave >> 1, wn = wave & 1;          // 2x2 wave grid, 64x64 each
    const int m0 = blockIdx.y * 128, n0 = blockIdx.x * 128;

    f32x4 acc[4][4];
    for (int i = 0; i < 4; i++)
        for (int j = 0; j < 4; j++) acc[i][j] = f32x4{0.f, 0.f, 0.f, 0.f};

    for (int k0 = 0; k0 < Kdim; k0 += 32) {
        for (int c = 0; c < 2; c++) {
            int e = c * 2048 + tid * 8;               // flat elem in [128][32] tile
            int row = e >> 5, col = e & 31;
            const float* ap = A + (size_t)(m0 + row) * Kdim + k0 + col;
            float4 f0 = *(const float4*)ap;
            float4 f1 = *(const float4*)(ap + 4);
            *(uint4*)(As + e) = pack8(f0, f1);
            *(uint4*)(Bs + e) = *(const uint4*)(Bt + (size_t)(n0 + row) * Kdim + k0 + col);
        }
        __syncthreads();
        bf16x8 af[4], bfr[4];
        for (int t = 0; t < 4; t++) af[t]  = ld8(As + (wm * 64 + t * 16 + ln) * 32 + g * 8);
        for (int t = 0; t < 4; t++) bfr[t] = ld8(Bs + (wn * 64 + t * 16 + ln) * 32 + g * 8);
        for (int mt = 0; mt < 4; mt++)
            for (int nt = 0; nt < 4; nt++)
                acc[mt][nt] = __builtin_amdgcn_mfma_f32_16x16x32_bf16(af[mt], bfr[nt], acc[mt][nt], 0, 0, 0);
        __syncthreads();
    }

    // epilogue: C/D layout col=lane&15, row=(lane>>4)*4+reg
    for (int mt = 0; mt < 4; mt++)
        for (int nt = 0; nt < 4; nt++)
            for (int r = 0; r < 4; r++) {
                int m = m0 + wm * 64 + mt * 16 + g * 4 + r;
                int n = n0 + wn * 64 + nt * 16 + ln;
                float val = acc[mt][nt][r] + bias[n];
                if (mode == 0) {
                    int which = n >> 10, rem = n & 1023;
                    int hh = rem >> 6, dd = rem & 63;
                    int b = m >> 11, s = m & 2047;
                    int bh = (b << 4) + hh;
                    if (which == 0)      qo[((size_t)bh * S + s) * DH + dd] = f2bf(val);
                    else if (which == 1) ko[((size_t)bh * S + s) * DH + dd] = f2bf(val);
                    else                 vo[((size_t)bh * DH + dd) * S + s] = f2bf(val);  // V^T
                } else {
                    outf[(size_t)m * 1024 + n] = val;
                }
            }
}

// ---------- flash attention: LDS-staged K/V shared by 4 waves, paired tiles -----
// Block = 4 waves, processes tile p then tile 31-p sequentially (17 uniform
// j-iters). Per j-iter: stage K[128x64]+V^T[64x128] to padded LDS (once, shared),
// each wave computes 16 q-rows. P aliases the K buffer (barrier after QK).
// LDS 34.3 KB -> 4 blocks/CU; grid 1024 = exact residency, uniform finish.
// bh = lin&63 => same-bh blocks land on same XCD (lin%8 const) for K/V L2 reuse.
__global__ __launch_bounds__(256, 4) void attn_fwd(const unsigned short* __restrict__ qg,
                                                   const unsigned short* __restrict__ kg,
                                                   const unsigned short* __restrict__ vtg,
                                                   float* __restrict__ og) {
    __shared__ __align__(16) unsigned short KP[128 * 68];  // K tile [128][68]; P aliases [64][132]
    __shared__ __align__(16) unsigned short Vs[64 * 132];  // V^T tile [64][132]
    const int lin = blockIdx.x;
    const int bh = lin & 63, p = lin >> 6;
    const int b = bh >> 4, h = bh & 15;
    const size_t base = (size_t)bh * S * DH;
    const unsigned short* qp  = qg  + base;
    const unsigned short* kp  = kg  + base;
    const unsigned short* vtp = vtg + base;               // [DH][S]
    const int tid = threadIdx.x, wave = tid >> 6, lane = tid & 63;
    const int g = lane >> 4, ln = lane & 15;

#pragma unroll 1
    for (int phase = 0; phase < 2; phase++) {
        const int qt = phase ? (31 - p) : p;
        const int q0 = qt * 64;
        const int jn = (qt >> 1) + 1;
        // Q B-frags for this wave's 16 q-rows (B-layout: n=ln, k=g*8+..)
        bf16x8 qf[2];
#pragma unroll
        for (int kc = 0; kc < 2; kc++)
            qf[kc] = ld8(qp + (size_t)(q0 + wave * 16 + ln) * DH + kc * 32 + g * 8);

        f32x4 o[4];
#pragma unroll
        for (int dt = 0; dt < 4; dt++) o[dt] = f32x4{0.f, 0.f, 0.f, 0.f};
        float m_ = -1e30f, l_ = 0.f;

#pragma unroll 1
        for (int j = 0; j < jn; j++) {
            // ---- stage K[j] (128x64) and V^T[:,j-tile] (64x128) into padded LDS
            const unsigned short* kj = kp + (size_t)j * 128 * DH;
            const unsigned short* vj = vtp + j * 128;
#pragma unroll
            for (int c = 0; c < 4; c++) {
                int e = c * 2048 + tid * 8;
                uint4 kv = *(const uint4*)(kj + e);
                *(uint4*)&KP[(e >> 6) * 68 + (e & 63)] = kv;
                int vr = e >> 7, vc = e & 127;
                uint4 vv = *(const uint4*)(vj + (size_t)vr * S + vc);
                *(uint4*)&Vs[vr * 132 + vc] = vv;
            }
            __syncthreads();

            // ---- S^T = K·Q^T : st[mt] C-layout kv=mt*16+g*4+r, qcol=ln
            f32x4 st[8];
#pragma unroll
            for (int mt = 0; mt < 8; mt++) {
                bf16x8 kf0 = ld8(&KP[(mt * 16 + ln) * 68 + g * 8]);
                bf16x8 kf1 = ld8(&KP[(mt * 16 + ln) * 68 + 32 + g * 8]);
                f32x4 t = f32x4{0.f, 0.f, 0.f, 0.f};
                t = __builtin_amdgcn_mfma_f32_16x16x32_bf16(kf0, qf[0], t, 0, 0, 0);
                t = __builtin_amdgcn_mfma_f32_16x16x32_bf16(kf1, qf[1], t, 0, 0, 0);
                st[mt] = t;
            }
            __syncthreads();   // all waves done reading K before P overwrites it

            if (j == jn - 1) {   // diagonal: mask kv_global > q_global
#pragma unroll
                for (int mt = 0; mt < 8; mt++)
#pragma unroll
                    for (int r = 0; r < 4; r++) {
                        int kvg = j * 128 + mt * 16 + g * 4 + r;
                        int qgl = q0 + wave * 16 + ln;
                        if (kvg > qgl) st[mt][r] = -3e38f;
                    }
            }
            // ---- online softmax (stats per lane, col=ln; reduce across g via shfl)
            f32x4 mm = st[0];
#pragma unroll
            for (int mt = 1; mt < 8; mt++)
#pragma unroll
                for (int e = 0; e < 4; e++) mm[e] = fmaxf(mm[e], st[mt][e]);
            float mx = fmaxf(fmaxf(mm[0], mm[1]), fmaxf(mm[2], mm[3]));
            mx = fmaxf(mx, __shfl_xor(mx, 16));
            mx = fmaxf(mx, __shfl_xor(mx, 32));
            float mnew = fmaxf(m_, mx);
            float alpha = __expf((m_ - mnew) * 0.125f);
            f32x4 sv = f32x4{0.f, 0.f, 0.f, 0.f};
#pragma unroll
            for (int mt = 0; mt < 8; mt++) {
                f32x4 pr;
#pragma unroll
                for (int e = 0; e < 4; e++) pr[e] = __expf((st[mt][e] - mnew) * 0.125f);
                st[mt] = pr;
                sv += pr;
            }
            float rs = (sv[0] + sv[1]) + (sv[2] + sv[3]);
            rs += __shfl_xor(rs, 16);
            rs += __shfl_xor(rs, 32);
            l_ = l_ * alpha + rs;
            m_ = mnew;

            // ---- pack P (truncate f32->bf16), write transposed rows [q=wave*16+ln][kv]
#pragma unroll
            for (int mt = 0; mt < 8; mt++) {
                uint4 u = __builtin_bit_cast(uint4, st[mt]);
                uint2 w;
                w.x = (u.y & 0xFFFF0000u) | (u.x >> 16);
                w.y = (u.w & 0xFFFF0000u) | (u.z >> 16);
                *(uint2*)&KP[(wave * 16 + ln) * 132 + mt * 16 + g * 4] = w;
            }
            // ---- rescale O rows (row=g*4+r) by alpha from stat lane ln'=g*4+r
#pragma unroll
            for (int r = 0; r < 4; r++) {
                float a = __shfl(alpha, (lane & 48) + g * 4 + r);
#pragma unroll
                for (int dt = 0; dt < 4; dt++) o[dt][r] *= a;
            }
            // ---- O += P·V  (P same-wave LDS rows; V^T shared LDS)
#pragma unroll
            for (int kc = 0; kc < 4; kc++) {
                bf16x8 pf = ld8(&KP[(wave * 16 + ln) * 132 + kc * 32 + g * 8]);
                bf16x8 vf[4];
#pragma unroll
                for (int dt = 0; dt < 4; dt++)
                    vf[dt] = ld8(&Vs[(dt * 16 + ln) * 132 + kc * 32 + g * 8]);
#pragma unroll
                for (int dt = 0; dt < 4; dt++)
                    o[dt] = __builtin_amdgcn_mfma_f32_16x16x32_bf16(pf, vf[dt], o[dt], 0, 0, 0);
            }
            __syncthreads();   // all waves done with P/V before next stage
        }

        // ---- epilogue: row g*4+r takes 1/l from stat lane ln'=g*4+r
#pragma unroll
        for (int r = 0; r < 4; r++) {
            float il = 1.f / __shfl(l_, (lane & 48) + g * 4 + r);
            int srow = q0 + wave * 16 + g * 4 + r;
#pragma unroll
            for (int dt = 0; dt < 4; dt++)
                og[((size_t)(b * S + srow)) * D + h * DH + dt * 16 + ln] = o[dt][r] * il;
        }
    }
}

extern "C" void kernel_launch(void* const* d_in, const int* in_sizes, int n_in,
                              void* d_out, int out_size, void* d_ws, size_t ws_size,
                              hipStream_t stream) {
    (void)in_sizes; (void)n_in; (void)out_size; (void)ws_size;
    const float* x      = (const float*)d_in[0];  // [B,S,D] f32
    const float* w_attn = (const float*)d_in[1];  // [D,3D]  f32
    const float* b_attn = (const float*)d_in[2];  // [3D]    f32
    const float* w_proj = (const float*)d_in[3];  // [D,D]   f32
    const float* b_proj = (const float*)d_in[4];  // [D]     f32

    char* ws = (char*)d_ws;
    unsigned short* wattn_t = (unsigned short*)ws;                       // [3072][1024] bf16
    unsigned short* wproj_t = (unsigned short*)(ws + 6291456);           // [1024][1024] bf16
    unsigned short* qb      = (unsigned short*)(ws + 8388608);           // [B,H,S,DH] bf16
    unsigned short* kb      = (unsigned short*)(ws + 8388608 + 16777216);
    unsigned short* vtb     = (unsigned short*)(ws + 8388608 + 2 * 16777216); // [B,H,DH,S] bf16
    float*          ao      = (float*)         (ws + 8388608 + 3 * 16777216); // [B,S,D] f32

    transpose_cvt<<<dim3(96, 32), 256, 0, stream>>>(w_attn, wattn_t, 1024, 3072);
    transpose_cvt<<<dim3(32, 32), 256, 0, stream>>>(w_proj, wproj_t, 1024, 1024);
    gemm_bt<<<dim3(24, 64), 256, 0, stream>>>(x, wattn_t, b_attn, 0, qb, kb, vtb, nullptr);
    attn_fwd<<<dim3(1024), 256, 0, stream>>>(qb, kb, vtb, ao);
    gemm_bt<<<dim3(8, 64), 256, 0, stream>>>(ao, wproj_t, b_proj, 1,
                                             nullptr, nullptr, nullptr, (float*)d_out);
}

// Round 6
// 403.148 us; speedup vs baseline: 1.3802x; 1.3802x over previous
//
#include <hip/hip_runtime.h>
#include <stdint.h>

typedef __bf16 bf16x8 __attribute__((ext_vector_type(8)));
typedef float  f32x4  __attribute__((ext_vector_type(4)));

#define DEV __device__ __forceinline__

constexpr int Bc = 4, S = 2048, D = 1024, Hh = 16, DH = 64;
constexpr int Kdim = 1024;   // inner K of both GEMMs

DEV unsigned short f2bf(float f) {
    uint32_t u = __builtin_bit_cast(uint32_t, f);
    u += 0x7fff + ((u >> 16) & 1);   // RNE
    return (unsigned short)(u >> 16);
}
DEV bf16x8 ld8(const unsigned short* p) {
    uint4 u = *(const uint4*)p;
    return __builtin_bit_cast(bf16x8, u);
}
DEV uint4 pack8(float4 a, float4 b) {
    union { uint4 u; unsigned short s[8]; } r;
    r.s[0] = f2bf(a.x); r.s[1] = f2bf(a.y); r.s[2] = f2bf(a.z); r.s[3] = f2bf(a.w);
    r.s[4] = f2bf(b.x); r.s[5] = f2bf(b.y); r.s[6] = f2bf(b.z); r.s[7] = f2bf(b.w);
    return r.u;
}

// ---------- weight transpose + cvt (f32 [rows][cols] -> bf16 [cols][rows]) ------
__global__ __launch_bounds__(256) void transpose_cvt(const float* __restrict__ in,
                                                     unsigned short* __restrict__ out,
                                                     int rows, int cols) {
    __shared__ float t[32][33];
    int tx = threadIdx.x & 31, ty = threadIdx.x >> 5;  // 32 x 8
    int c = blockIdx.x * 32 + tx;
    int rbase = blockIdx.y * 32;
    for (int rr = 0; rr < 32; rr += 8)
        t[ty + rr][tx] = in[(size_t)(rbase + ty + rr) * cols + c];
    __syncthreads();
    int orbase = blockIdx.x * 32;
    for (int rr = 0; rr < 32; rr += 8)
        out[(size_t)(orbase + ty + rr) * rows + rbase + tx] = f2bf(t[tx][ty + rr]);
}

// ---------- GEMM: C[M,N] = A_f32[M,K] * Bt_bf16[N,K]^T + bias_f32 ---------------
// mode 0: scatter bf16 into q/k [B,H,S,DH] and V TRANSPOSED [B,H,DH,S]
// mode 1: write f32 outf [M,N]
__global__ __launch_bounds__(256) void gemm_bt(const float* __restrict__ A,
                                               const unsigned short* __restrict__ Bt,
                                               const float* __restrict__ bias,
                                               int mode,
                                               unsigned short* __restrict__ qo,
                                               unsigned short* __restrict__ ko,
                                               unsigned short* __restrict__ vo,
                                               float* __restrict__ outf) {
    __shared__ __align__(16) unsigned short As[128 * 32];
    __shared__ __align__(16) unsigned short Bs[128 * 32];
    const int tid = threadIdx.x;
    const int wave = tid >> 6, lane = tid & 63, g = lane >> 4, ln = lane & 15;
    const int wm = wave >> 1, wn = wave & 1;          // 2x2 wave grid, 64x64 each
    const int m0 = blockIdx.y * 128, n0 = blockIdx.x * 128;

    f32x4 acc[4][4];
    for (int i = 0; i < 4; i++)
        for (int j = 0; j < 4; j++) acc[i][j] = f32x4{0.f, 0.f, 0.f, 0.f};

    for (int k0 = 0; k0 < Kdim; k0 += 32) {
        for (int c = 0; c < 2; c++) {
            int e = c * 2048 + tid * 8;               // flat elem in [128][32] tile
            int row = e >> 5, col = e & 31;
            const float* ap = A + (size_t)(m0 + row) * Kdim + k0 + col;
            float4 f0 = *(const float4*)ap;
            float4 f1 = *(const float4*)(ap + 4);
            *(uint4*)(As + e) = pack8(f0, f1);
            *(uint4*)(Bs + e) = *(const uint4*)(Bt + (size_t)(n0 + row) * Kdim + k0 + col);
        }
        __syncthreads();
        bf16x8 af[4], bfr[4];
        for (int t = 0; t < 4; t++) af[t]  = ld8(As + (wm * 64 + t * 16 + ln) * 32 + g * 8);
        for (int t = 0; t < 4; t++) bfr[t] = ld8(Bs + (wn * 64 + t * 16 + ln) * 32 + g * 8);
        for (int mt = 0; mt < 4; mt++)
            for (int nt = 0; nt < 4; nt++)
                acc[mt][nt] = __builtin_amdgcn_mfma_f32_16x16x32_bf16(af[mt], bfr[nt], acc[mt][nt], 0, 0, 0);
        __syncthreads();
    }

    // epilogue: C/D layout col=lane&15, row=(lane>>4)*4+reg
    for (int mt = 0; mt < 4; mt++)
        for (int nt = 0; nt < 4; nt++)
            for (int r = 0; r < 4; r++) {
                int m = m0 + wm * 64 + mt * 16 + g * 4 + r;
                int n = n0 + wn * 64 + nt * 16 + ln;
                float val = acc[mt][nt][r] + bias[n];
                if (mode == 0) {
                    int which = n >> 10, rem = n & 1023;
                    int hh = rem >> 6, dd = rem & 63;
                    int b = m >> 11, s = m & 2047;
                    int bh = (b << 4) + hh;
                    if (which == 0)      qo[((size_t)bh * S + s) * DH + dd] = f2bf(val);
                    else if (which == 1) ko[((size_t)bh * S + s) * DH + dd] = f2bf(val);
                    else                 vo[((size_t)bh * DH + dd) * S + s] = f2bf(val);  // V^T
                } else {
                    outf[(size_t)m * 1024 + n] = val;
                }
            }
}

// ---------- flash attention: register-pipelined staging, per-lane softmax -------
// Block = 4 waves, one 64-row q-tile (qt), jn = qt/2+1 kv-iters, heavy-first.
// Wave owns 16 q-rows. S^T = K*Q^T (C cols = q = lane&15 -> stats per lane).
// O kept transposed (O^T = V^T * P^T); transposed back via LDS in epilogue.
// K(j+1)/V(j+1) prefetched into registers at top of iter j, ds_written at the
// end after the read-barrier -> global latency covered by a full iteration.
__global__ __launch_bounds__(256, 3) void attn_fwd(const unsigned short* __restrict__ qg,
                                                   const unsigned short* __restrict__ kg,
                                                   const unsigned short* __restrict__ vtg,
                                                   float* __restrict__ og) {
    __shared__ __align__(16) unsigned short Ks[128 * 72];  // K tile [128][64] pad->72
    __shared__ __align__(16) unsigned short Vs[64 * 136];  // V^T tile [64][128] pad->136
    __shared__ __align__(16) unsigned short P [64 * 136];  // probs [64 q][128 kv], per-wave rows
    const int idx = blockIdx.x;
    const int qt = 31 - (idx >> 6);                        // heavy tiles dispatch first
    const int bh = idx & 63;                               // idx%8 = bh%8 -> same-bh same XCD
    const int b = bh >> 4, h = bh & 15;
    const size_t base = (size_t)bh * S * DH;
    const unsigned short* qp  = qg  + base;
    const unsigned short* kp  = kg  + base;
    const unsigned short* vtp = vtg + base;                // [DH][S]
    const int tid = threadIdx.x, wave = tid >> 6, lane = tid & 63;
    const int g = lane >> 4, ln = lane & 15;
    const int q0 = qt * 64, wq = wave * 16;                // wave's q rows [q0+wq, +16)
    const int jn = (qt >> 1) + 1;

    // Q B-frag (B-layout: n=ln -> q=q0+wq+ln; k=kc*32+g*8+j)
    bf16x8 qf[2];
    qf[0] = ld8(qp + (size_t)(q0 + wq + ln) * DH + g * 8);
    qf[1] = ld8(qp + (size_t)(q0 + wq + ln) * DH + 32 + g * 8);

    // ---- stage tile 0
    uint4 kpre[4], vpre[4];
#pragma unroll
    for (int c = 0; c < 4; c++) {
        int e = c * 2048 + tid * 8;
        kpre[c] = *(const uint4*)(kp + e);                           // K rows [0..128)
        vpre[c] = *(const uint4*)(vtp + (size_t)(e >> 7) * S + (e & 127));
    }
#pragma unroll
    for (int c = 0; c < 4; c++) {
        int e = c * 2048 + tid * 8;
        *(uint4*)&Ks[(e >> 6) * 72 + (e & 63)] = kpre[c];
        *(uint4*)&Vs[(e >> 7) * 136 + (e & 127)] = vpre[c];
    }

    f32x4 o_t[4];
#pragma unroll
    for (int dt = 0; dt < 4; dt++) o_t[dt] = f32x4{0.f, 0.f, 0.f, 0.f};
    float m_ = -1e30f, l_ = 0.f;
    __syncthreads();

#pragma unroll 1
    for (int j = 0; j < jn; j++) {
        // ---- prefetch next K/V tiles into registers (latency covered by this iter)
        if (j + 1 < jn) {
            const unsigned short* kj = kp + (size_t)(j + 1) * 128 * DH;
            const unsigned short* vj = vtp + (j + 1) * 128;
#pragma unroll
            for (int c = 0; c < 4; c++) {
                int e = c * 2048 + tid * 8;
                kpre[c] = *(const uint4*)(kj + e);
                vpre[c] = *(const uint4*)(vj + (size_t)(e >> 7) * S + (e & 127));
            }
        }
        // ---- S^T = K*Q^T : st[mt] C-layout kv=mt*16+g*4+r, q-col=ln
        f32x4 st[8];
#pragma unroll
        for (int mt = 0; mt < 8; mt++) {
            bf16x8 kf0 = ld8(&Ks[(mt * 16 + ln) * 72 + g * 8]);
            bf16x8 kf1 = ld8(&Ks[(mt * 16 + ln) * 72 + 32 + g * 8]);
            f32x4 t = f32x4{0.f, 0.f, 0.f, 0.f};
            t = __builtin_amdgcn_mfma_f32_16x16x32_bf16(kf0, qf[0], t, 0, 0, 0);
            t = __builtin_amdgcn_mfma_f32_16x16x32_bf16(kf1, qf[1], t, 0, 0, 0);
            st[mt] = t;
        }
        if (j == jn - 1) {   // diagonal: mask kv_global > q_global
            int qgl = q0 + wq + ln;
#pragma unroll
            for (int mt = 0; mt < 8; mt++)
#pragma unroll
                for (int r = 0; r < 4; r++) {
                    int kvg = j * 128 + mt * 16 + g * 4 + r;
                    if (kvg > qgl) st[mt][r] = -3e38f;
                }
        }
        // ---- online softmax: q = ln is lane-resident; kv spread over (g, mt, r)
        f32x4 mm = st[0];
#pragma unroll
        for (int mt = 1; mt < 8; mt++)
#pragma unroll
            for (int e = 0; e < 4; e++) mm[e] = fmaxf(mm[e], st[mt][e]);
        float mx = fmaxf(fmaxf(mm[0], mm[1]), fmaxf(mm[2], mm[3]));
        mx = fmaxf(mx, __shfl_xor(mx, 16));
        mx = fmaxf(mx, __shfl_xor(mx, 32));
        float mnew = fmaxf(m_, mx);
        float alpha = __expf((m_ - mnew) * 0.125f);
        f32x4 sv = f32x4{0.f, 0.f, 0.f, 0.f};
#pragma unroll
        for (int mt = 0; mt < 8; mt++) {
            f32x4 pr;
#pragma unroll
            for (int e = 0; e < 4; e++) pr[e] = __expf((st[mt][e] - mnew) * 0.125f);
            st[mt] = pr;
            sv += pr;
        }
        float rs = (sv[0] + sv[1]) + (sv[2] + sv[3]);
        rs += __shfl_xor(rs, 16);
        rs += __shfl_xor(rs, 32);
        l_ = l_ * alpha + rs;
        m_ = mnew;

        // ---- pack P (truncate f32->bf16) into [q][kv] rows (wave-private)
#pragma unroll
        for (int mt = 0; mt < 8; mt++) {
            uint4 u = __builtin_bit_cast(uint4, st[mt]);
            uint2 w;
            w.x = (u.y & 0xFFFF0000u) | (u.x >> 16);
            w.y = (u.w & 0xFFFF0000u) | (u.z >> 16);
            *(uint2*)&P[(wq + ln) * 136 + mt * 16 + g * 4] = w;
        }
        // ---- rescale O^T (cols = q = ln): plain per-lane vector multiply
#pragma unroll
        for (int dt = 0; dt < 4; dt++) o_t[dt] *= alpha;

        // ---- O^T += V^T * P^T (A = V^T from shared LDS, B = P^T from wave rows)
#pragma unroll
        for (int kc = 0; kc < 4; kc++) {
            bf16x8 pf = ld8(&P[(wq + ln) * 136 + kc * 32 + g * 8]);
            bf16x8 vf[4];
#pragma unroll
            for (int dt = 0; dt < 4; dt++)
                vf[dt] = ld8(&Vs[(dt * 16 + ln) * 136 + kc * 32 + g * 8]);
#pragma unroll
            for (int dt = 0; dt < 4; dt++)
                o_t[dt] = __builtin_amdgcn_mfma_f32_16x16x32_bf16(vf[dt], pf, o_t[dt], 0, 0, 0);
        }
        __syncthreads();   // all waves done reading Ks/Vs (and own P)
        if (j + 1 < jn) {
#pragma unroll
            for (int c = 0; c < 4; c++) {
                int e = c * 2048 + tid * 8;
                *(uint4*)&Ks[(e >> 6) * 72 + (e & 63)] = kpre[c];
                *(uint4*)&Vs[(e >> 7) * 136 + (e & 127)] = vpre[c];
            }
        }
        __syncthreads();   // staged writes visible before next iter's reads
    }

    // ---- epilogue: scale 1/l (per lane), transpose O^T via wave-private LDS,
    //      coalesced f32 stores. Wave region = P rows [wq..wq+16) = [16][68] f32.
    float il = 1.f / l_;
#pragma unroll
    for (int dt = 0; dt < 4; dt++) o_t[dt] *= il;
    float* Ot = (float*)&P[wq * 136];
#pragma unroll
    for (int dt = 0; dt < 4; dt++)
        *(float4*)&Ot[ln * 68 + dt * 16 + g * 4] =
            float4{o_t[dt][0], o_t[dt][1], o_t[dt][2], o_t[dt][3]};
    // same-wave LDS RAW: DS ops are in-order per wave
#pragma unroll
    for (int i = 0; i < 4; i++) {
        float4 v = *(float4*)&Ot[(i * 4 + g) * 68 + ln * 4];
        *(float4*)&og[((size_t)(b * S + q0 + wq + i * 4 + g)) * D + h * DH + ln * 4] = v;
    }
}

extern "C" void kernel_launch(void* const* d_in, const int* in_sizes, int n_in,
                              void* d_out, int out_size, void* d_ws, size_t ws_size,
                              hipStream_t stream) {
    (void)in_sizes; (void)n_in; (void)out_size; (void)ws_size;
    const float* x      = (const float*)d_in[0];  // [B,S,D] f32
    const float* w_attn = (const float*)d_in[1];  // [D,3D]  f32
    const float* b_attn = (const float*)d_in[2];  // [3D]    f32
    const float* w_proj = (const float*)d_in[3];  // [D,D]   f32
    const float* b_proj = (const float*)d_in[4];  // [D]     f32

    char* ws = (char*)d_ws;
    unsigned short* wattn_t = (unsigned short*)ws;                       // [3072][1024] bf16
    unsigned short* wproj_t = (unsigned short*)(ws + 6291456);           // [1024][1024] bf16
    unsigned short* qb      = (unsigned short*)(ws + 8388608);           // [B,H,S,DH] bf16
    unsigned short* kb      = (unsigned short*)(ws + 8388608 + 16777216);
    unsigned short* vtb     = (unsigned short*)(ws + 8388608 + 2 * 16777216); // [B,H,DH,S] bf16
    float*          ao      = (float*)         (ws + 8388608 + 3 * 16777216); // [B,S,D] f32

    transpose_cvt<<<dim3(96, 32), 256, 0, stream>>>(w_attn, wattn_t, 1024, 3072);
    transpose_cvt<<<dim3(32, 32), 256, 0, stream>>>(w_proj, wproj_t, 1024, 1024);
    gemm_bt<<<dim3(24, 64), 256, 0, stream>>>(x, wattn_t, b_attn, 0, qb, kb, vtb, nullptr);
    attn_fwd<<<dim3(2048), 256, 0, stream>>>(qb, kb, vtb, ao);
    gemm_bt<<<dim3(8, 64), 256, 0, stream>>>(ao, wproj_t, b_proj, 1,
                                             nullptr, nullptr, nullptr, (float*)d_out);
}